// Round 1
// baseline (237.343 us; speedup 1.0000x reference)
//
#include <hip/hip_runtime.h>
#include <hip/hip_bf16.h>

#define SEQ 2048
#define BATCH 4
#define HID 1024

typedef __bf16 bf16x8 __attribute__((ext_vector_type(8)));
typedef float f32x4 __attribute__((ext_vector_type(4)));

__device__ __forceinline__ void gload_lds16(void* lds, const void* g) {
  __builtin_amdgcn_global_load_lds(
      (const __attribute__((address_space(1))) void*)g,
      (__attribute__((address_space(3))) void*)lds, 16, 0, 0);
}

// ---------------- cast fp32 -> bf16, 8 elems/thread ----------------
__global__ __launch_bounds__(256) void cast_f32_bf16(const float* __restrict__ in,
                                                     __bf16* __restrict__ out, int n8) {
  int i = blockIdx.x * 256 + threadIdx.x;
  if (i >= n8) return;
  const float4* p = (const float4*)in + (size_t)i * 2;
  float4 a = p[0], b = p[1];
  bf16x8 v;
  v[0] = (__bf16)a.x; v[1] = (__bf16)a.y; v[2] = (__bf16)a.z; v[3] = (__bf16)a.w;
  v[4] = (__bf16)b.x; v[5] = (__bf16)b.y; v[6] = (__bf16)b.z; v[7] = (__bf16)b.w;
  ((bf16x8*)out)[i] = v;
}

// ---------------- generic 128x128x(K) B^T GEMM, bf16 MFMA ----------------
// A: [M][K] row-major (lda), per-z offset sAz (elements)
// B: [N][K] row-major (ldb), per-z offset sBz — dot of rows (B^T GEMM)
// EPI 0: Q/K proj: dst bf16 [z][s][h], +bias(aux)
// EPI 1: V proj:   dst bf16 [z][h][s] (transposed), +bias(aux)
// EPI 2: scores:   dst fp32 [z][q][k] = acc/32 * ssm(aux)[z][q][k]
// EPI 3: PV:       dst fp32 out[(q*BATCH+z)*HID + h] = acc
template<int EPI>
__global__ __launch_bounds__(256)
void gemm_bt(const __bf16* __restrict__ A, int lda, long long sAz,
             const __bf16* __restrict__ B, int ldb, long long sBz,
             const float* __restrict__ aux, void* __restrict__ dst, int K)
{
  __shared__ __bf16 As[2][128 * 32];
  __shared__ __bf16 Bs[2][128 * 32];
  const int tid = threadIdx.x;
  const int wid = tid >> 6, lane = tid & 63;
  const int wr = wid >> 1, wc = wid & 1;
  const int m0 = blockIdx.x * 128, n0 = blockIdx.y * 128;
  const int z = blockIdx.z;
  const __bf16* Ab = A + (size_t)z * sAz;
  const __bf16* Bb = B + (size_t)z * sBz;

  const int srow = (wid * 2) * 16 + (lane >> 2);  // staging row (j=0 chunk)
  const int scol = (lane & 3) * 8;                // staging col (elements)

  auto stage = [&](int buf, int kt) {
    const int k0 = kt * 32;
#pragma unroll
    for (int j = 0; j < 2; ++j) {
      const int row = srow + j * 16;
      const int chunk = wid * 2 + j;
      gload_lds16(&As[buf][chunk * 512], Ab + (size_t)(m0 + row) * lda + k0 + scol);
      gload_lds16(&Bs[buf][chunk * 512], Bb + (size_t)(n0 + row) * ldb + k0 + scol);
    }
  };

  f32x4 acc[4][4] = {};
  const int nk = K >> 5;
  stage(0, 0);
  __syncthreads();
  for (int kt = 0; kt < nk; ++kt) {
    const int buf = kt & 1;
    if (kt + 1 < nk) stage(buf ^ 1, kt + 1);
    const int fr = lane & 15, fc = (lane >> 4) * 8;
    bf16x8 af[4], bfr[4];
#pragma unroll
    for (int mi = 0; mi < 4; ++mi)
      af[mi] = *(const bf16x8*)&As[buf][(wr * 64 + mi * 16 + fr) * 32 + fc];
#pragma unroll
    for (int ni = 0; ni < 4; ++ni)
      bfr[ni] = *(const bf16x8*)&Bs[buf][(wc * 64 + ni * 16 + fr) * 32 + fc];
#pragma unroll
    for (int mi = 0; mi < 4; ++mi)
#pragma unroll
      for (int ni = 0; ni < 4; ++ni)
        acc[mi][ni] = __builtin_amdgcn_mfma_f32_16x16x32_bf16(af[mi], bfr[ni], acc[mi][ni], 0, 0, 0);
    __syncthreads();
  }

  // epilogue: D row = (lane>>4)*4 + r, col = lane&15  [m89-verified layout]
  const int fr = lane & 15, fq = lane >> 4;
#pragma unroll
  for (int mi = 0; mi < 4; ++mi) {
#pragma unroll
    for (int ni = 0; ni < 4; ++ni) {
      const int gn = n0 + wc * 64 + ni * 16 + fr;
      const int gmb = m0 + wr * 64 + mi * 16 + fq * 4;
      f32x4 v = acc[mi][ni];
      float bias = (EPI == 0 || EPI == 1) ? aux[gn] : 0.f;
#pragma unroll
      for (int r = 0; r < 4; ++r) {
        const int gm = gmb + r;
        if (EPI == 0) {
          ((__bf16*)dst)[(size_t)z * SEQ * HID + (size_t)gm * HID + gn] = (__bf16)(v[r] + bias);
        } else if (EPI == 1) {
          ((__bf16*)dst)[(size_t)z * HID * SEQ + (size_t)gn * SEQ + gm] = (__bf16)(v[r] + bias);
        } else if (EPI == 2) {
          const size_t idx = (size_t)z * SEQ * SEQ + (size_t)gm * SEQ + gn;
          ((float*)dst)[idx] = v[r] * 0.03125f * aux[idx];
        } else {
          ((float*)dst)[((size_t)gm * BATCH + z) * HID + gn] = v[r];
        }
      }
    }
  }
}

// ---------------- row softmax (in-place: fp32 row -> bf16 P at row head) ----------------
__global__ __launch_bounds__(256)
void softmax_rows(float* __restrict__ S) {
  const int row = blockIdx.x;
  float* rp = S + (size_t)row * SEQ;
  const int t = threadIdx.x;
  float4 a = ((const float4*)rp)[t * 2];
  float4 b = ((const float4*)rp)[t * 2 + 1];
  float v[8] = {a.x, a.y, a.z, a.w, b.x, b.y, b.z, b.w};
  float mx = v[0];
#pragma unroll
  for (int j = 1; j < 8; ++j) mx = fmaxf(mx, v[j]);
#pragma unroll
  for (int off = 32; off; off >>= 1) mx = fmaxf(mx, __shfl_xor(mx, off));
  __shared__ float redm[4], reds[4];
  const int wid = t >> 6, lane = t & 63;
  if (lane == 0) redm[wid] = mx;
  __syncthreads();
  mx = fmaxf(fmaxf(redm[0], redm[1]), fmaxf(redm[2], redm[3]));
  float e[8], s = 0.f;
#pragma unroll
  for (int j = 0; j < 8; ++j) { e[j] = __expf(v[j] - mx); s += e[j]; }
#pragma unroll
  for (int off = 32; off; off >>= 1) s += __shfl_xor(s, off);
  if (lane == 0) reds[wid] = s;
  __syncthreads();
  s = reds[0] + reds[1] + reds[2] + reds[3];
  const float inv = 1.f / s;
  bf16x8 p;
#pragma unroll
  for (int j = 0; j < 8; ++j) p[j] = (__bf16)(e[j] * inv);
  ((bf16x8*)rp)[t] = p;  // all reads done before barriers above
}

extern "C" void kernel_launch(void* const* d_in, const int* in_sizes, int n_in,
                              void* d_out, int out_size, void* d_ws, size_t ws_size,
                              hipStream_t stream) {
  const float* x   = (const float*)d_in[0];
  const float* ssm = (const float*)d_in[1];
  const float* Wq  = (const float*)d_in[2];
  const float* bq  = (const float*)d_in[3];
  const float* Wk  = (const float*)d_in[4];
  const float* bk  = (const float*)d_in[5];
  const float* Wv  = (const float*)d_in[6];
  const float* bv  = (const float*)d_in[7];
  float* out = (float*)d_out;

  // workspace layout (≈140.5 MB)
  __bf16* xbf = (__bf16*)d_ws;                       // 8192*1024
  __bf16* wqb = xbf + (size_t)SEQ * BATCH * HID;     // 1024*1024
  __bf16* wkb = wqb + (size_t)HID * HID;
  __bf16* wvb = wkb + (size_t)HID * HID;
  __bf16* Qb  = wvb + (size_t)HID * HID;             // [b][s][h]
  __bf16* Kb  = Qb + (size_t)BATCH * SEQ * HID;      // [b][s][h]
  __bf16* Vt  = Kb + (size_t)BATCH * SEQ * HID;      // [b][h][s]
  float*  S   = (float*)(Vt + (size_t)BATCH * SEQ * HID);  // [b][q][k] fp32 (P bf16 in-place)

  // casts
  cast_f32_bf16<<<SEQ * BATCH * HID / 8 / 256, 256, 0, stream>>>(x, xbf, SEQ * BATCH * HID / 8);
  cast_f32_bf16<<<HID * HID / 8 / 256, 256, 0, stream>>>(Wq, wqb, HID * HID / 8);
  cast_f32_bf16<<<HID * HID / 8 / 256, 256, 0, stream>>>(Wk, wkb, HID * HID / 8);
  cast_f32_bf16<<<HID * HID / 8 / 256, 256, 0, stream>>>(Wv, wvb, HID * HID / 8);

  // QKV projections, per-batch view of x: A = xbf + b*HID, lda = BATCH*HID
  dim3 gp(SEQ / 128, HID / 128, BATCH);
  gemm_bt<0><<<gp, 256, 0, stream>>>(xbf, BATCH * HID, HID, wqb, HID, 0, bq, Qb, HID);
  gemm_bt<0><<<gp, 256, 0, stream>>>(xbf, BATCH * HID, HID, wkb, HID, 0, bk, Kb, HID);
  gemm_bt<1><<<gp, 256, 0, stream>>>(xbf, BATCH * HID, HID, wvb, HID, 0, bv, Vt, HID);

  // scores: S[b][q][k] = (Q·K)/32 * ssm
  dim3 gs(SEQ / 128, SEQ / 128, BATCH);
  gemm_bt<2><<<gs, 256, 0, stream>>>(Qb, HID, (long long)SEQ * HID,
                                     Kb, HID, (long long)SEQ * HID, ssm, S, HID);

  // softmax rows -> bf16 P in-place (row stride 4096 bf16)
  softmax_rows<<<BATCH * SEQ, 256, 0, stream>>>(S);

  // PV: out[q][b][h] = P·V  (A = P bf16 lda 4096, B = Vt [h][s])
  dim3 gv(SEQ / 128, HID / 128, BATCH);
  gemm_bt<3><<<gv, 256, 0, stream>>>((const __bf16*)S, 2 * SEQ, (long long)SEQ * 2 * SEQ,
                                     Vt, SEQ, (long long)HID * SEQ, nullptr, out, SEQ);
}

// Round 2
// 208.784 us; speedup vs baseline: 1.1368x; 1.1368x over previous
//
#include <hip/hip_runtime.h>
#include <hip/hip_bf16.h>

#define SEQ 2048
#define BATCH 4
#define HID 1024

typedef __bf16 bf16x8 __attribute__((ext_vector_type(8)));
typedef float f32x4 __attribute__((ext_vector_type(4)));

__device__ __forceinline__ void gload_lds16(void* lds, const void* g) {
  __builtin_amdgcn_global_load_lds(
      (const __attribute__((address_space(1))) void*)g,
      (__attribute__((address_space(3))) void*)lds, 16, 0, 0);
}

// ---------------- cast fp32 -> bf16, 8 elems/thread ----------------
__global__ __launch_bounds__(256) void cast_f32_bf16(const float* __restrict__ in,
                                                     __bf16* __restrict__ out, int n8) {
  int i = blockIdx.x * 256 + threadIdx.x;
  if (i >= n8) return;
  const float4* p = (const float4*)in + (size_t)i * 2;
  float4 a = p[0], b = p[1];
  bf16x8 v;
  v[0] = (__bf16)a.x; v[1] = (__bf16)a.y; v[2] = (__bf16)a.z; v[3] = (__bf16)a.w;
  v[4] = (__bf16)b.x; v[5] = (__bf16)b.y; v[6] = (__bf16)b.z; v[7] = (__bf16)b.w;
  ((bf16x8*)out)[i] = v;
}

// cast 3 weight matrices into one contiguous [3*HID][HID] bf16 buffer
__global__ __launch_bounds__(256) void cast_w3(const float* __restrict__ w0,
                                               const float* __restrict__ w1,
                                               const float* __restrict__ w2,
                                               __bf16* __restrict__ out) {
  const int wsel = blockIdx.y;
  const float* src = wsel == 0 ? w0 : wsel == 1 ? w1 : w2;
  int i = blockIdx.x * 256 + threadIdx.x;  // i < HID*HID/8 = 131072
  const float4* p = (const float4*)src + (size_t)i * 2;
  float4 a = p[0], b = p[1];
  bf16x8 v;
  v[0] = (__bf16)a.x; v[1] = (__bf16)a.y; v[2] = (__bf16)a.z; v[3] = (__bf16)a.w;
  v[4] = (__bf16)b.x; v[5] = (__bf16)b.y; v[6] = (__bf16)b.z; v[7] = (__bf16)b.w;
  ((bf16x8*)(out + (size_t)wsel * HID * HID))[i] = v;
}

__global__ void concat_bias(const float* b0, const float* b1, const float* b2,
                            float* __restrict__ out) {
  const float* s = blockIdx.x == 0 ? b0 : blockIdx.x == 1 ? b1 : b2;
  out[blockIdx.x * HID + threadIdx.x] = s[threadIdx.x];
}

// ---------------- generic 128x128x(K) B^T GEMM, bf16 MFMA ----------------
// A: [M][K] row-major (lda), per-z offset sAz; B: [N][K] row-major (ldb), per-z sBz
// EPI 0: merged QKV proj. aux=bias[3072]; dst=Q base; Q/K -> [z][s][h]+bias,
//        V -> transposed [z][h][s]+bias (at dst + 2*BATCH*SEQ*HID)
// EPI 2: exp-scores: e = exp(acc/32 * ssm) -> bf16 dst [z][q][k] (ld SEQ);
//        per-row partial sums over this 128-col block -> aux2[(z*SEQ+q)*16 + blockIdx.y]
// EPI 3: PV: out[(q*BATCH+z)*HID+h] = acc * (1/rowsum) ; aux = partial sums
template<int EPI>
__global__ __launch_bounds__(256)
void gemm_bt(const __bf16* __restrict__ A, int lda, long long sAz,
             const __bf16* __restrict__ B, int ldb, long long sBz,
             const float* __restrict__ aux, void* __restrict__ dst,
             float* __restrict__ aux2, int K)
{
  __shared__ __bf16 As[2][128 * 32];
  __shared__ __bf16 Bs[2][128 * 32];
  const int tid = threadIdx.x;
  const int wid = tid >> 6, lane = tid & 63;
  const int wr = wid >> 1, wc = wid & 1;
  const int m0 = blockIdx.x * 128, n0 = blockIdx.y * 128;
  const int z = blockIdx.z;
  const __bf16* Ab = A + (size_t)z * sAz;
  const __bf16* Bb = B + (size_t)z * sBz;

  const int srow = (wid * 2) * 16 + (lane >> 2);  // staging row (j=0 chunk)
  const int scol = (lane & 3) * 8;                // staging col (elements)

  auto stage = [&](int buf, int kt) {
    const int k0 = kt * 32;
#pragma unroll
    for (int j = 0; j < 2; ++j) {
      const int row = srow + j * 16;
      const int chunk = wid * 2 + j;
      gload_lds16(&As[buf][chunk * 512], Ab + (size_t)(m0 + row) * lda + k0 + scol);
      gload_lds16(&Bs[buf][chunk * 512], Bb + (size_t)(n0 + row) * ldb + k0 + scol);
    }
  };

  f32x4 acc[4][4] = {};
  const int nk = K >> 5;
  stage(0, 0);
  __syncthreads();
  for (int kt = 0; kt < nk; ++kt) {
    const int buf = kt & 1;
    if (kt + 1 < nk) stage(buf ^ 1, kt + 1);
    const int fr = lane & 15, fc = (lane >> 4) * 8;
    bf16x8 af[4], bfr[4];
#pragma unroll
    for (int mi = 0; mi < 4; ++mi)
      af[mi] = *(const bf16x8*)&As[buf][(wr * 64 + mi * 16 + fr) * 32 + fc];
#pragma unroll
    for (int ni = 0; ni < 4; ++ni)
      bfr[ni] = *(const bf16x8*)&Bs[buf][(wc * 64 + ni * 16 + fr) * 32 + fc];
#pragma unroll
    for (int mi = 0; mi < 4; ++mi)
#pragma unroll
      for (int ni = 0; ni < 4; ++ni)
        acc[mi][ni] = __builtin_amdgcn_mfma_f32_16x16x32_bf16(af[mi], bfr[ni], acc[mi][ni], 0, 0, 0);
    __syncthreads();
  }

  // D layout: row = (lane>>4)*4 + r, col = lane&15 within each 16x16 frag
  const int fr = lane & 15, fq = lane >> 4;

  if (EPI == 0) {
    const int hsel = n0 >> 10;  // uniform per block: 0=Q,1=K,2=V
#pragma unroll
    for (int mi = 0; mi < 4; ++mi) {
#pragma unroll
      for (int ni = 0; ni < 4; ++ni) {
        const int gn = n0 + wc * 64 + ni * 16 + fr;
        const int h = gn & (HID - 1);
        const int gmb = m0 + wr * 64 + mi * 16 + fq * 4;
        const float bias = aux[gn];
        f32x4 v = acc[mi][ni];
#pragma unroll
        for (int r = 0; r < 4; ++r) {
          const int gm = gmb + r;
          if (hsel < 2) {
            ((__bf16*)dst)[(size_t)hsel * BATCH * SEQ * HID + (size_t)z * SEQ * HID +
                           (size_t)gm * HID + h] = (__bf16)(v[r] + bias);
          } else {
            ((__bf16*)dst)[(size_t)2 * BATCH * SEQ * HID + (size_t)z * HID * SEQ +
                           (size_t)h * SEQ + gm] = (__bf16)(v[r] + bias);
          }
        }
      }
    }
  } else if (EPI == 2) {
    float psum[4][4];
#pragma unroll
    for (int mi = 0; mi < 4; ++mi)
#pragma unroll
      for (int r = 0; r < 4; ++r) psum[mi][r] = 0.f;
#pragma unroll
    for (int mi = 0; mi < 4; ++mi) {
#pragma unroll
      for (int ni = 0; ni < 4; ++ni) {
        const int gn = n0 + wc * 64 + ni * 16 + fr;
        const int gmb = m0 + wr * 64 + mi * 16 + fq * 4;
        f32x4 v = acc[mi][ni];
#pragma unroll
        for (int r = 0; r < 4; ++r) {
          const size_t idx = (size_t)z * SEQ * SEQ + (size_t)(gmb + r) * SEQ + gn;
          const float e = __expf(v[r] * 0.03125f * aux[idx]);
          ((__bf16*)dst)[idx] = (__bf16)e;
          psum[mi][r] += e;
        }
      }
    }
    // sum over the 16 fr-lanes (bits 0..3) -> per-row sum over this wave's 64 cols
#pragma unroll
    for (int mi = 0; mi < 4; ++mi)
#pragma unroll
      for (int r = 0; r < 4; ++r) {
        float s = psum[mi][r];
        s += __shfl_xor(s, 1); s += __shfl_xor(s, 2);
        s += __shfl_xor(s, 4); s += __shfl_xor(s, 8);
        psum[mi][r] = s;
      }
    float* red = (float*)&As[0][0];  // k-loop done; safe to reuse (loop ends with barrier)
    if (fr == 0) {
#pragma unroll
      for (int mi = 0; mi < 4; ++mi)
#pragma unroll
        for (int r = 0; r < 4; ++r)
          red[wid * 64 + mi * 16 + fq * 4 + r] = psum[mi][r];
    }
    __syncthreads();
    if (tid < 128) {
      const int wrr = tid >> 6, r64 = tid & 63;
      const float s = red[(wrr * 2) * 64 + r64] + red[(wrr * 2 + 1) * 64 + r64];
      aux2[((size_t)z * SEQ + m0 + tid) * 16 + blockIdx.y] = s;
    }
  } else {  // EPI == 3
    float* red = (float*)&As[0][0];
    if (tid < 128) {
      const float* pp = aux + ((size_t)z * SEQ + m0 + tid) * 16;
      float s = 0.f;
#pragma unroll
      for (int j = 0; j < 16; ++j) s += pp[j];
      red[tid] = 1.f / s;
    }
    __syncthreads();
#pragma unroll
    for (int mi = 0; mi < 4; ++mi) {
#pragma unroll
      for (int ni = 0; ni < 4; ++ni) {
        const int gn = n0 + wc * 64 + ni * 16 + fr;
        const int rbase = wr * 64 + mi * 16 + fq * 4;
        f32x4 v = acc[mi][ni];
#pragma unroll
        for (int r = 0; r < 4; ++r) {
          const int gm = m0 + rbase + r;
          ((float*)dst)[((size_t)gm * BATCH + z) * HID + gn] = v[r] * red[rbase + r];
        }
      }
    }
  }
}

extern "C" void kernel_launch(void* const* d_in, const int* in_sizes, int n_in,
                              void* d_out, int out_size, void* d_ws, size_t ws_size,
                              hipStream_t stream) {
  const float* x   = (const float*)d_in[0];
  const float* ssm = (const float*)d_in[1];
  const float* Wq  = (const float*)d_in[2];
  const float* bq  = (const float*)d_in[3];
  const float* Wk  = (const float*)d_in[4];
  const float* bk  = (const float*)d_in[5];
  const float* Wv  = (const float*)d_in[6];
  const float* bv  = (const float*)d_in[7];
  float* out = (float*)d_out;

  const size_t BSH = (size_t)BATCH * SEQ * HID;
  // fp32 regions first
  float* bqkv    = (float*)d_ws;                    // 4096 floats (3072 used)
  float* partial = bqkv + 4096;                     // BATCH*SEQ*16 = 131072 floats
  __bf16* xbf  = (__bf16*)(partial + (size_t)BATCH * SEQ * 16);  // SEQ*BATCH*HID
  __bf16* wqkv = xbf + BSH * 2;                     // wait: xbf is SEQ*BATCH*HID = BSH*... no
  // xbf has SEQ*BATCH*HID = BSH elements (BATCH*SEQ*HID == SEQ*BATCH*HID)
  wqkv = xbf + BSH;                                 // 3*HID*HID
  __bf16* Qb = wqkv + (size_t)3 * HID * HID;        // Q | K | Vt contiguous, 3*BSH
  __bf16* Kb = Qb + BSH;
  __bf16* Vt = Qb + 2 * BSH;
  __bf16* E  = Qb + 3 * BSH;                        // BATCH*SEQ*SEQ bf16

  // casts
  cast_f32_bf16<<<(int)(BSH / 8 / 256), 256, 0, stream>>>(x, xbf, (int)(BSH / 8));
  cast_w3<<<dim3(HID * HID / 8 / 256, 3), 256, 0, stream>>>(Wq, Wk, Wv, wqkv);
  concat_bias<<<3, HID, 0, stream>>>(bq, bk, bv, bqkv);

  // merged QKV projection: A = per-batch view of x (lda BATCH*HID), B = wqkv [3072][1024]
  dim3 gp(SEQ / 128, 3 * HID / 128, BATCH);
  gemm_bt<0><<<gp, 256, 0, stream>>>(xbf, BATCH * HID, HID, wqkv, HID, 0, bqkv, Qb, nullptr, HID);

  // exp-scores: E[b][q][k] = exp(Q·K/32 * ssm), partial row sums
  dim3 gs(SEQ / 128, SEQ / 128, BATCH);
  gemm_bt<2><<<gs, 256, 0, stream>>>(Qb, HID, (long long)SEQ * HID,
                                     Kb, HID, (long long)SEQ * HID, ssm, E, partial, HID);

  // PV: out[q][b][h] = (E·V) / rowsum
  dim3 gv(SEQ / 128, HID / 128, BATCH);
  gemm_bt<3><<<gv, 256, 0, stream>>>(E, SEQ, (long long)SEQ * SEQ,
                                     Vt, SEQ, (long long)HID * SEQ, partial, out, nullptr, SEQ);
}

// Round 3
// 165.378 us; speedup vs baseline: 1.4352x; 1.2625x over previous
//
#include <hip/hip_runtime.h>
#include <hip/hip_bf16.h>

#define SEQ 2048
#define BATCH 4
#define HID 1024

typedef __bf16 bf16x8 __attribute__((ext_vector_type(8)));
typedef __bf16 bf16x4 __attribute__((ext_vector_type(4)));
typedef float f32x4 __attribute__((ext_vector_type(4)));

__device__ __forceinline__ void gload_lds16(void* lds, const void* g) {
  __builtin_amdgcn_global_load_lds(
      (const __attribute__((address_space(1))) void*)g,
      (__attribute__((address_space(3))) void*)lds, 16, 0, 0);
}

// ---------------- cast fp32 -> bf16, 8 elems/thread ----------------
__global__ __launch_bounds__(256) void cast_f32_bf16(const float* __restrict__ in,
                                                     __bf16* __restrict__ out, int n8) {
  int i = blockIdx.x * 256 + threadIdx.x;
  if (i >= n8) return;
  const float4* p = (const float4*)in + (size_t)i * 2;
  float4 a = p[0], b = p[1];
  bf16x8 v;
  v[0] = (__bf16)a.x; v[1] = (__bf16)a.y; v[2] = (__bf16)a.z; v[3] = (__bf16)a.w;
  v[4] = (__bf16)b.x; v[5] = (__bf16)b.y; v[6] = (__bf16)b.z; v[7] = (__bf16)b.w;
  ((bf16x8*)out)[i] = v;
}

__global__ __launch_bounds__(256) void cast_w3(const float* __restrict__ w0,
                                               const float* __restrict__ w1,
                                               const float* __restrict__ w2,
                                               __bf16* __restrict__ out) {
  const int wsel = blockIdx.y;
  const float* src = wsel == 0 ? w0 : wsel == 1 ? w1 : w2;
  int i = blockIdx.x * 256 + threadIdx.x;
  const float4* p = (const float4*)src + (size_t)i * 2;
  float4 a = p[0], b = p[1];
  bf16x8 v;
  v[0] = (__bf16)a.x; v[1] = (__bf16)a.y; v[2] = (__bf16)a.z; v[3] = (__bf16)a.w;
  v[4] = (__bf16)b.x; v[5] = (__bf16)b.y; v[6] = (__bf16)b.z; v[7] = (__bf16)b.w;
  ((bf16x8*)(out + (size_t)wsel * HID * HID))[i] = v;
}

__global__ void concat_bias(const float* b0, const float* b1, const float* b2,
                            float* __restrict__ out) {
  const float* s = blockIdx.x == 0 ? b0 : blockIdx.x == 1 ? b1 : b2;
  out[blockIdx.x * HID + threadIdx.x] = s[threadIdx.x];
}

// ============ 8-wave 128x256xK B^T GEMM, 3-slot ring, counted vmcnt ============
// A:[M][K] (lda, per-z sAz), B:[N][K] (ldb, per-z sBz), dot of rows.
// EPI 0: QKV proj; aux=bias[3072]; Q/K -> [z][s][h]+bias, V -> [z][h][s]+bias
// EPI 2: e=exp(acc/32*ssm) -> bf16 [z][q][k]; row partials -> aux2[row*8+by]
// EPI 3: out[(q*BATCH+z)*HID+h] = acc / rowsum(aux)
#define SLOT 49152  // A 128x64x2 = 16384 B, B 256x64x2 = 32768 B
template<int EPI>
__global__ __launch_bounds__(512, 2)
void gemm8(const __bf16* __restrict__ A, int lda, long long sAz,
           const __bf16* __restrict__ B, int ldb, long long sBz,
           const float* __restrict__ aux, void* __restrict__ dst,
           float* __restrict__ aux2, int K)
{
  __shared__ __align__(16) char lds[3 * SLOT];
  const int tid = threadIdx.x;
  const int wid = tid >> 6, lane = tid & 63;
  const int wr = wid >> 2, wc = wid & 3;
  const int m0 = blockIdx.x * 128, n0 = blockIdx.y * 256;
  const int z = blockIdx.z;
  const __bf16* Ab = A + (size_t)z * sAz;
  const __bf16* Bb = B + (size_t)z * sBz;

  // ---- staging: linear LDS dest, inverse-swizzled global source (rule #21) ----
  const int srow = tid >> 3;                                  // 0..63
  const int scol = ((tid & 7) * 16) ^ ((srow & 7) << 4);      // swizzled byte col
  const char* asrc0 = (const char*)(Ab + (size_t)(m0 + srow) * lda) + scol;
  const char* asrc1 = (const char*)(Ab + (size_t)(m0 + srow + 64) * lda) + scol;
  const char* bsrc0 = (const char*)(Bb + (size_t)(n0 + srow) * ldb) + scol;
  const char* bsrc1 = (const char*)(Bb + (size_t)(n0 + srow + 64) * ldb) + scol;
  const char* bsrc2 = (const char*)(Bb + (size_t)(n0 + srow + 128) * ldb) + scol;
  const char* bsrc3 = (const char*)(Bb + (size_t)(n0 + srow + 192) * ldb) + scol;
  const int dA = tid * 16, dB = 16384 + tid * 16;

  // ---- swizzled ds_read offsets: frag (row, ksub): byte = row*128 + ((fc2+ks*64)^((fr&7)<<4)) ----
  const int fr = lane & 15, fq = lane >> 4;
  const int fc2 = fq * 16;
  const int swz = (fr & 7) << 4;
  int aoff[4][2], boff[4][2];
#pragma unroll
  for (int mi = 0; mi < 4; ++mi) {
    const int row = wr * 64 + mi * 16 + fr;
#pragma unroll
    for (int ks = 0; ks < 2; ++ks)
      aoff[mi][ks] = row * 128 + ((fc2 + ks * 64) ^ swz);
  }
#pragma unroll
  for (int ni = 0; ni < 4; ++ni) {
    const int row = wc * 64 + ni * 16 + fr;
#pragma unroll
    for (int ks = 0; ks < 2; ++ks)
      boff[ni][ks] = 16384 + row * 128 + ((fc2 + ks * 64) ^ swz);
  }

  const int nk = K >> 6;
  // prologue: fully stage tiles 0 and 1 (12 loads in flight)
  {
    char* s0 = lds;
    gload_lds16(s0 + dA, asrc0); gload_lds16(s0 + dA + 8192, asrc1);
    gload_lds16(s0 + dB, bsrc0); gload_lds16(s0 + dB + 8192, bsrc1);
    gload_lds16(s0 + dB + 16384, bsrc2); gload_lds16(s0 + dB + 24576, bsrc3);
    char* s1 = lds + SLOT;
    gload_lds16(s1 + dA, asrc0 + 128); gload_lds16(s1 + dA + 8192, asrc1 + 128);
    gload_lds16(s1 + dB, bsrc0 + 128); gload_lds16(s1 + dB + 8192, bsrc1 + 128);
    gload_lds16(s1 + dB + 16384, bsrc2 + 128); gload_lds16(s1 + dB + 24576, bsrc3 + 128);
  }

  f32x4 acc[4][4] = {};
  for (int t = 0; t < nk; ++t) {
    char* s = lds + (t % 3) * SLOT;
    // wait for tile t's loads (t+1's 6 stay in flight), then all-wave visibility
    if (t + 1 < nk) asm volatile("s_waitcnt vmcnt(6)" ::: "memory");
    else            asm volatile("s_waitcnt vmcnt(0)" ::: "memory");
    __builtin_amdgcn_s_barrier();
    asm volatile("" ::: "memory");

    bf16x8 a[4][2], b[4][2];
    // ---- phase 0: read A(all) + B(n0,n1); stage t+2 part 1; MFMA ni 0..1 ----
#pragma unroll
    for (int mi = 0; mi < 4; ++mi)
#pragma unroll
      for (int ks = 0; ks < 2; ++ks)
        a[mi][ks] = *(const bf16x8*)(s + aoff[mi][ks]);
#pragma unroll
    for (int ni = 0; ni < 2; ++ni)
#pragma unroll
      for (int ks = 0; ks < 2; ++ks)
        b[ni][ks] = *(const bf16x8*)(s + boff[ni][ks]);
    if (t + 2 < nk) {
      char* sn = lds + ((t + 2) % 3) * SLOT;
      const size_t ko = (size_t)(t + 2) * 128;
      gload_lds16(sn + dA, asrc0 + ko);
      gload_lds16(sn + dA + 8192, asrc1 + ko);
      gload_lds16(sn + dB, bsrc0 + ko);
    }
    asm volatile("" ::: "memory");
    __builtin_amdgcn_s_barrier();
    asm volatile("s_waitcnt lgkmcnt(0)" ::: "memory");
    __builtin_amdgcn_sched_barrier(0);
    __builtin_amdgcn_s_setprio(1);
#pragma unroll
    for (int mi = 0; mi < 4; ++mi)
#pragma unroll
      for (int ni = 0; ni < 2; ++ni)
#pragma unroll
        for (int ks = 0; ks < 2; ++ks)
          acc[mi][ni] = __builtin_amdgcn_mfma_f32_16x16x32_bf16(a[mi][ks], b[ni][ks], acc[mi][ni], 0, 0, 0);
    __builtin_amdgcn_s_setprio(0);
    asm volatile("" ::: "memory");
    __builtin_amdgcn_s_barrier();
    asm volatile("" ::: "memory");

    // ---- phase 1: read B(n2,n3); stage t+2 part 2; MFMA ni 2..3 ----
#pragma unroll
    for (int ni = 2; ni < 4; ++ni)
#pragma unroll
      for (int ks = 0; ks < 2; ++ks)
        b[ni][ks] = *(const bf16x8*)(s + boff[ni][ks]);
    if (t + 2 < nk) {
      char* sn = lds + ((t + 2) % 3) * SLOT;
      const size_t ko = (size_t)(t + 2) * 128;
      gload_lds16(sn + dB + 8192, bsrc1 + ko);
      gload_lds16(sn + dB + 16384, bsrc2 + ko);
      gload_lds16(sn + dB + 24576, bsrc3 + ko);
    }
    asm volatile("" ::: "memory");
    __builtin_amdgcn_s_barrier();
    asm volatile("s_waitcnt lgkmcnt(0)" ::: "memory");
    __builtin_amdgcn_sched_barrier(0);
    __builtin_amdgcn_s_setprio(1);
#pragma unroll
    for (int mi = 0; mi < 4; ++mi)
#pragma unroll
      for (int ni = 2; ni < 4; ++ni)
#pragma unroll
        for (int ks = 0; ks < 2; ++ks)
          acc[mi][ni] = __builtin_amdgcn_mfma_f32_16x16x32_bf16(a[mi][ks], b[ni][ks], acc[mi][ni], 0, 0, 0);
    __builtin_amdgcn_s_setprio(0);
    // loop top provides vmcnt + barrier for next tile
  }
  __syncthreads();  // full drain before LDS reuse in epilogues

  // ---- epilogues; D frag: row=(lane>>4)*4+r, col=lane&15 ----
  if (EPI == 0) {
    const int hsel = n0 >> 10;  // block-uniform: 0=Q,1=K,2=V
    const size_t BSH = (size_t)BATCH * SEQ * HID;
#pragma unroll
    for (int mi = 0; mi < 4; ++mi) {
#pragma unroll
      for (int ni = 0; ni < 4; ++ni) {
        const int gn = n0 + wc * 64 + ni * 16 + fr;
        const int h = gn & (HID - 1);
        const int gmb = m0 + wr * 64 + mi * 16 + fq * 4;
        const float bias = aux[gn];
        f32x4 v = acc[mi][ni];
        if (hsel < 2) {
#pragma unroll
          for (int r = 0; r < 4; ++r)
            ((__bf16*)dst)[(size_t)hsel * BSH + (size_t)z * SEQ * HID +
                           (size_t)(gmb + r) * HID + h] = (__bf16)(v[r] + bias);
        } else {
          bf16x4 vv;
#pragma unroll
          for (int r = 0; r < 4; ++r) vv[r] = (__bf16)(v[r] + bias);
          *(bf16x4*)&((__bf16*)dst)[2 * BSH + (size_t)z * HID * SEQ +
                                    (size_t)h * SEQ + gmb] = vv;
        }
      }
    }
  } else if (EPI == 2) {
    float psum[4][4] = {};
#pragma unroll
    for (int mi = 0; mi < 4; ++mi) {
#pragma unroll
      for (int ni = 0; ni < 4; ++ni) {
        const int gn = n0 + wc * 64 + ni * 16 + fr;
        const int gmb = m0 + wr * 64 + mi * 16 + fq * 4;
        f32x4 v = acc[mi][ni];
#pragma unroll
        for (int r = 0; r < 4; ++r) {
          const size_t idx = (size_t)z * SEQ * SEQ + (size_t)(gmb + r) * SEQ + gn;
          const float e = __expf(v[r] * 0.03125f * aux[idx]);
          ((__bf16*)dst)[idx] = (__bf16)e;
          psum[mi][r] += e;
        }
      }
    }
    // reduce over the 16 fr lanes
#pragma unroll
    for (int mi = 0; mi < 4; ++mi)
#pragma unroll
      for (int r = 0; r < 4; ++r) {
        float sv = psum[mi][r];
        sv += __shfl_xor(sv, 1); sv += __shfl_xor(sv, 2);
        sv += __shfl_xor(sv, 4); sv += __shfl_xor(sv, 8);
        psum[mi][r] = sv;
      }
    float* red = (float*)lds;  // 8 waves x 64 rows
    if (fr == 0) {
#pragma unroll
      for (int mi = 0; mi < 4; ++mi)
#pragma unroll
        for (int r = 0; r < 4; ++r)
          red[wid * 64 + mi * 16 + fq * 4 + r] = psum[mi][r];
    }
    __syncthreads();
    if (tid < 128) {
      const int half = tid >> 6, r64 = tid & 63;
      float sv = 0.f;
#pragma unroll
      for (int j = 0; j < 4; ++j) sv += red[(half * 4 + j) * 64 + r64];
      aux2[((size_t)z * SEQ + m0 + tid) * 8 + blockIdx.y] = sv;
    }
  } else {  // EPI == 3
    float* red = (float*)lds;
    if (tid < 128) {
      const float* pp = aux + ((size_t)z * SEQ + m0 + tid) * 8;
      float sv = 0.f;
#pragma unroll
      for (int j = 0; j < 8; ++j) sv += pp[j];
      red[tid] = 1.f / sv;
    }
    __syncthreads();
#pragma unroll
    for (int mi = 0; mi < 4; ++mi) {
#pragma unroll
      for (int ni = 0; ni < 4; ++ni) {
        const int gn = n0 + wc * 64 + ni * 16 + fr;
        const int rbase = wr * 64 + mi * 16 + fq * 4;
        f32x4 v = acc[mi][ni];
#pragma unroll
        for (int r = 0; r < 4; ++r)
          ((float*)dst)[((size_t)(m0 + rbase + r) * BATCH + z) * HID + gn] = v[r] * red[rbase + r];
      }
    }
  }
}

extern "C" void kernel_launch(void* const* d_in, const int* in_sizes, int n_in,
                              void* d_out, int out_size, void* d_ws, size_t ws_size,
                              hipStream_t stream) {
  const float* x   = (const float*)d_in[0];
  const float* ssm = (const float*)d_in[1];
  const float* Wq  = (const float*)d_in[2];
  const float* bq  = (const float*)d_in[3];
  const float* Wk  = (const float*)d_in[4];
  const float* bk  = (const float*)d_in[5];
  const float* Wv  = (const float*)d_in[6];
  const float* bv  = (const float*)d_in[7];
  float* out = (float*)d_out;

  const size_t BSH = (size_t)BATCH * SEQ * HID;
  float* bqkv    = (float*)d_ws;                               // 4096 floats
  float* partial = bqkv + 4096;                                // BATCH*SEQ*8
  __bf16* xbf  = (__bf16*)(partial + (size_t)BATCH * SEQ * 8);
  __bf16* wqkv = xbf + BSH;
  __bf16* Qb = wqkv + (size_t)3 * HID * HID;                   // Q | K | Vt
  __bf16* Kb = Qb + BSH;
  __bf16* Vt = Qb + 2 * BSH;
  __bf16* E  = Qb + 3 * BSH;                                   // [b][q][k] bf16

  cast_f32_bf16<<<(int)(BSH / 8 / 256), 256, 0, stream>>>(x, xbf, (int)(BSH / 8));
  cast_w3<<<dim3(HID * HID / 8 / 256, 3), 256, 0, stream>>>(Wq, Wk, Wv, wqkv);
  concat_bias<<<3, HID, 0, stream>>>(bq, bk, bv, bqkv);

  // QKV: A = per-batch view of x (lda BATCH*HID), B = wqkv [3072][1024]
  gemm8<0><<<dim3(16, 12, BATCH), 512, 0, stream>>>(xbf, BATCH * HID, HID,
                                                    wqkv, HID, 0, bqkv, Qb, nullptr, HID);
  // scores: E = exp(Q.K/32 * ssm), partial row sums
  gemm8<2><<<dim3(16, 8, BATCH), 512, 0, stream>>>(Qb, HID, (long long)SEQ * HID,
                                                   Kb, HID, (long long)SEQ * HID,
                                                   ssm, E, partial, HID);
  // PV: out[q][b][h] = (E.V) / rowsum
  gemm8<3><<<dim3(16, 4, BATCH), 512, 0, stream>>>(E, SEQ, (long long)SEQ * SEQ,
                                                   Vt, SEQ, (long long)HID * SEQ,
                                                   partial, out, nullptr, SEQ);
}